// Round 1
// baseline (2950.981 us; speedup 1.0000x reference)
//
#include <hip/hip_runtime.h>
#include <hip/hip_bf16.h>
#include <math.h>

#define D 96
#define H 8
#define KH 12
#define S 32

__device__ __forceinline__ float sigmoidf_(float x) { return 1.0f / (1.0f + __expf(-x)); }
__device__ __forceinline__ float siluf_(float x) { return x * sigmoidf_(x); }
__device__ __forceinline__ float slrelu_(float x) {
    // (1+a)/2 * x + (1-a)/2 * x * (2*sigmoid(x)-1), a = 0.2
    float s = sigmoidf_(x);
    return 0.6f * x + 0.4f * x * (2.0f * s - 1.0f);
}

// ---------------------------------------------------------------------------
// K1: radial MLP + depthwise product:  msg = message * edge_attr * (silu(xs@W1+b1)@W2+b2)
// 64 edges per block, 256 threads.
// ---------------------------------------------------------------------------
__global__ __launch_bounds__(256) void radial_msg_kernel(
    const float* __restrict__ message, const float* __restrict__ ea,
    const float* __restrict__ xs, const float* __restrict__ W1,
    const float* __restrict__ b1, const float* __restrict__ W2,
    const float* __restrict__ b2, float* __restrict__ msg, int E)
{
    __shared__ float sW1[S * S];
    __shared__ float sW2[S * D];
    __shared__ float sb1[S];
    __shared__ float sb2[D];
    __shared__ float sxs[64 * (S + 1)];
    __shared__ float shid[64 * (S + 1)];

    const int t = threadIdx.x;
    const int row0 = blockIdx.x * 64;

    for (int i = t; i < S * S; i += 256) sW1[i] = W1[i];
    for (int i = t; i < S * D; i += 256) sW2[i] = W2[i];
    if (t < S) sb1[t] = b1[t];
    if (t < D) sb2[t] = b2[t];
    for (int i = t; i < 64 * S; i += 256) {
        int e = i / S, s = i % S;
        int r = row0 + e;
        sxs[e * (S + 1) + s] = (r < E) ? xs[(size_t)r * S + s] : 0.0f;
    }
    __syncthreads();

    for (int i = t; i < 64 * S; i += 256) {
        int e = i / S, j = i % S;
        float acc = sb1[j];
#pragma unroll
        for (int k = 0; k < S; k++) acc += sxs[e * (S + 1) + k] * sW1[k * S + j];
        shid[e * (S + 1) + j] = siluf_(acc);
    }
    __syncthreads();

    for (int i = t; i < 64 * D; i += 256) {
        int e = i / D, d = i % D;
        int r = row0 + e;
        if (r >= E) continue;
        float acc = sb2[d];
#pragma unroll
        for (int k = 0; k < S; k++) acc += shid[e * (S + 1) + k] * sW2[k * D + d];
        msg[(size_t)r * D + d] = message[(size_t)r * D + d] * ea[r] * acc;
    }
}

// ---------------------------------------------------------------------------
// Generic [rows,96] @ [96,96] GEMM, 64 rows per block, 192 threads.
// MODE 0: plain store. MODE 1: silu(x)*ea[row]*wd[d] store (in-place capable).
// MODE 2: smooth-leaky-relu -> dot with alpha_dot -> logits [rows, 8].
// src/dst intentionally NOT __restrict__ (in-place use).
// ---------------------------------------------------------------------------
template <int MODE>
__global__ __launch_bounds__(192) void gemm96_kernel(
    const float* src, const float* __restrict__ W, float* dst, int rows,
    const float* __restrict__ ea, const float* __restrict__ wd,
    const float* __restrict__ adot)
{
    __shared__ float sW[D * D];            // 36864 B
    __shared__ float tile[64 * (D + 1)];   // 24832 B (padded rows)

    const int t = threadIdx.x;
    const int row0 = blockIdx.x * 64;

    for (int i = t; i < D * D; i += 192) sW[i] = W[i];
    for (int i = t; i < 64 * D; i += 192) {
        int e = i / D, d = i % D;
        int r = row0 + e;
        tile[e * (D + 1) + d] = (r < rows) ? src[(size_t)r * D + d] : 0.0f;
    }
    __syncthreads();

    // thread -> 4 rows x 8 cols. eg = t&15 (16 row-groups), dg = t>>4 (12 col-groups)
    const int eg = t & 15;
    const int dg = t >> 4;
    const int e0 = eg * 4;
    const int d0 = dg * 8;

    float acc[4][8];
#pragma unroll
    for (int a = 0; a < 4; a++)
#pragma unroll
        for (int j = 0; j < 8; j++) acc[a][j] = 0.0f;

    for (int kk = 0; kk < D; kk++) {
        float4 w0 = *(const float4*)&sW[kk * D + d0];
        float4 w1 = *(const float4*)&sW[kk * D + d0 + 4];
#pragma unroll
        for (int a = 0; a < 4; a++) {
            float m = tile[(e0 + a) * (D + 1) + kk];
            acc[a][0] += m * w0.x; acc[a][1] += m * w0.y;
            acc[a][2] += m * w0.z; acc[a][3] += m * w0.w;
            acc[a][4] += m * w1.x; acc[a][5] += m * w1.y;
            acc[a][6] += m * w1.z; acc[a][7] += m * w1.w;
        }
    }

    if (MODE == 2) {
        // write smooth-leaky-relu values back into tile, then reduce per (e,h)
        __syncthreads();
#pragma unroll
        for (int a = 0; a < 4; a++)
#pragma unroll
            for (int j = 0; j < 8; j++)
                tile[(e0 + a) * (D + 1) + d0 + j] = slrelu_(acc[a][j]);
        __syncthreads();
        for (int i = t; i < 64 * H; i += 192) {
            int e = i / H, h = i % H;
            int r = row0 + e;
            if (r >= rows) continue;
            float lg = 0.0f;
#pragma unroll
            for (int k = 0; k < KH; k++) lg += tile[e * (D + 1) + h * KH + k] * adot[h * KH + k];
            dst[(size_t)r * H + h] = lg;
        }
    } else {
#pragma unroll
        for (int a = 0; a < 4; a++) {
            int r = row0 + e0 + a;
            if (r >= rows) continue;
            float scale = (MODE == 1) ? ea[r] : 1.0f;
            float4 o0, o1;
            float v0 = acc[a][0], v1 = acc[a][1], v2 = acc[a][2], v3 = acc[a][3];
            float v4 = acc[a][4], v5 = acc[a][5], v6 = acc[a][6], v7 = acc[a][7];
            if (MODE == 1) {
                v0 = siluf_(v0) * scale * wd[d0 + 0];
                v1 = siluf_(v1) * scale * wd[d0 + 1];
                v2 = siluf_(v2) * scale * wd[d0 + 2];
                v3 = siluf_(v3) * scale * wd[d0 + 3];
                v4 = siluf_(v4) * scale * wd[d0 + 4];
                v5 = siluf_(v5) * scale * wd[d0 + 5];
                v6 = siluf_(v6) * scale * wd[d0 + 6];
                v7 = siluf_(v7) * scale * wd[d0 + 7];
            }
            o0 = make_float4(v0, v1, v2, v3);
            o1 = make_float4(v4, v5, v6, v7);
            *(float4*)&dst[(size_t)r * D + d0] = o0;
            *(float4*)&dst[(size_t)r * D + d0 + 4] = o1;
        }
    }
}

// ---------------------------------------------------------------------------
// K4: segment log-sum-exp over sorted edge_dst. One thread per (node, head).
// ---------------------------------------------------------------------------
__global__ __launch_bounds__(256) void logz_kernel(
    const float* __restrict__ logits, const int* __restrict__ dst,
    float* __restrict__ logZ, int E, int N)
{
    int tid = blockIdx.x * 256 + threadIdx.x;
    if (tid >= N * H) return;
    int n = tid / H, h = tid % H;
    int lo = 0, hi = E;
    while (lo < hi) {
        int mid = (lo + hi) >> 1;
        if (dst[mid] < n) lo = mid + 1; else hi = mid;
    }
    float m = -INFINITY;
    int e = lo;
    while (e < E && dst[e] == n) { m = fmaxf(m, logits[(size_t)e * H + h]); e++; }
    float z = 0.0f;
    for (int e2 = lo; e2 < e; e2++) z += __expf(logits[(size_t)e2 * H + h] - m);
    logZ[tid] = m + __logf(z);   // -inf for empty segments (never consumed)
}

// ---------------------------------------------------------------------------
// K5: weighted segment-sum. One thread per (node, d). No atomics.
// ---------------------------------------------------------------------------
__global__ __launch_bounds__(256) void aggregate_kernel(
    const float* __restrict__ value, const float* __restrict__ logits,
    const float* __restrict__ logZ, const int* __restrict__ dst,
    float* __restrict__ attn, int E, int N)
{
    int tid = blockIdx.x * 256 + threadIdx.x;
    if (tid >= N * D) return;
    int n = tid / D, d = tid % D;
    int h = d / KH;
    int lo = 0, hi = E;
    while (lo < hi) {
        int mid = (lo + hi) >> 1;
        if (dst[mid] < n) lo = mid + 1; else hi = mid;
    }
    float lz = logZ[n * H + h];
    float acc = 0.0f;
    for (int e = lo; e < E && dst[e] == n; e++) {
        float a = __expf(logits[(size_t)e * H + h] - lz);
        acc += value[(size_t)e * D + d] * a;
    }
    attn[tid] = acc;
}

// ---------------------------------------------------------------------------
extern "C" void kernel_launch(void* const* d_in, const int* in_sizes, int n_in,
                              void* d_out, int out_size, void* d_ws, size_t ws_size,
                              hipStream_t stream)
{
    const float* message      = (const float*)d_in[0];
    const float* edge_attr    = (const float*)d_in[1];
    const float* edge_scalars = (const float*)d_in[2];
    const float* W_rad1       = (const float*)d_in[3];
    const float* b_rad1       = (const float*)d_in[4];
    const float* W_rad2       = (const float*)d_in[5];
    const float* b_rad2       = (const float*)d_in[6];
    const float* W_alpha      = (const float*)d_in[7];
    const float* W_lin        = (const float*)d_in[8];
    const float* w_dtp2       = (const float*)d_in[9];
    const float* W_lin2       = (const float*)d_in[10];
    const float* alpha_dot    = (const float*)d_in[11];
    const float* W_proj       = (const float*)d_in[12];
    const int*   edge_dst     = (const int*)d_in[13];
    float* out = (float*)d_out;

    const int E = in_sizes[0] / D;
    const int N = out_size / D;

    char* ws = (char*)d_ws;
    float* msg    = (float*)ws;                                        // E*96 f32, later holds value
    float* logits = (float*)(ws + (size_t)E * D * 4);                  // E*8 f32
    float* logZ   = (float*)(ws + (size_t)E * D * 4 + (size_t)E * H * 4);     // N*8 f32
    float* attn   = (float*)(ws + (size_t)E * D * 4 + (size_t)E * H * 4
                                + (size_t)N * H * 4);                  // N*96 f32

    const int ebl = (E + 63) / 64;
    const int nbl = (N + 63) / 64;

    radial_msg_kernel<<<ebl, 256, 0, stream>>>(message, edge_attr, edge_scalars,
                                               W_rad1, b_rad1, W_rad2, b_rad2, msg, E);
    // logits = einsum(smoothLeakyReLU(msg@W_alpha), alpha_dot)
    gemm96_kernel<2><<<ebl, 192, 0, stream>>>(msg, W_alpha, logits, E,
                                              nullptr, nullptr, alpha_dot);
    // msg <- silu(msg@W_lin) * ea * w_dtp2   (in-place)
    gemm96_kernel<1><<<ebl, 192, 0, stream>>>(msg, W_lin, msg, E,
                                              edge_attr, w_dtp2, nullptr);
    // msg <- msg @ W_lin2                    (in-place) == value
    gemm96_kernel<0><<<ebl, 192, 0, stream>>>(msg, W_lin2, msg, E,
                                              nullptr, nullptr, nullptr);
    // segment softmax normalizer
    logz_kernel<<<(N * H + 255) / 256, 256, 0, stream>>>(logits, edge_dst, logZ, E, N);
    // attn = segment_sum(value * alpha)
    aggregate_kernel<<<(N * D + 255) / 256, 256, 0, stream>>>(msg, logits, logZ,
                                                              edge_dst, attn, E, N);
    // out = attn @ W_proj
    gemm96_kernel<0><<<nbl, 192, 0, stream>>>(attn, W_proj, out, N,
                                              nullptr, nullptr, nullptr);
}

// Round 2
// 1037.687 us; speedup vs baseline: 2.8438x; 2.8438x over previous
//
#include <hip/hip_runtime.h>
#include <hip/hip_bf16.h>
#include <math.h>

#define D 96
#define H 8
#define KH 12
#define S 32

typedef __attribute__((ext_vector_type(8))) short short8;
typedef __attribute__((ext_vector_type(4))) float f32x4;

#define MFMA(a, b, c) __builtin_amdgcn_mfma_f32_16x16x32_bf16(a, b, c, 0, 0, 0)

__device__ __forceinline__ float sigmoidf_(float x) { return 1.0f / (1.0f + __expf(-x)); }
__device__ __forceinline__ float siluf_(float x) { return x * sigmoidf_(x); }
__device__ __forceinline__ float slrelu_(float x) {
    float s = sigmoidf_(x);
    return 0.6f * x + 0.4f * x * (2.0f * s - 1.0f);
}
// round-to-nearest-even f32 -> bf16 (bit pattern in a short)
__device__ __forceinline__ short f2bf(float f) {
    unsigned int u = __float_as_uint(f);
    u += 0x7fffu + ((u >> 16) & 1u);
    return (short)(u >> 16);
}
__device__ __forceinline__ float bf2f(ushort u) {
    return __uint_as_float(((unsigned int)u) << 16);
}

// ---------------------------------------------------------------------------
// Pack all weights into MFMA B-fragment-ready bf16 layout.
// Frag f-index table (each frag = 64 lanes x 8 shorts = 512 shorts):
//   0..1   W1    (32x32): t=fi,          f=0
//   2..7   W2    (32x96): t=fi-2,        f=0
//   8..25  Walpha(96x96): t=(fi-8)/3,    f=(fi-8)%3
//  26..43  Wlin  (96x96): t=(fi-26)/3,   f=(fi-26)%3
//  44..61  Wlin2 (96x96): t=(fi-44)/3,   f=(fi-44)%3
// Lane l holds B[k = f*32 + (l>>4)*8 + j][n = t*16 + (l&15)], j=0..7.
// ---------------------------------------------------------------------------
__global__ void pack_weights_kernel(
    const float* __restrict__ W1, const float* __restrict__ W2,
    const float* __restrict__ WA, const float* __restrict__ WL,
    const float* __restrict__ WL2, short* __restrict__ wB)
{
    int tid = blockIdx.x * 256 + threadIdx.x;
    if (tid >= 62 * 512) return;
    int j    = tid & 7;
    int lane = (tid >> 3) & 63;
    int fi   = tid >> 9;
    int q = lane >> 4, ln = lane & 15;
    const float* src; int ncols, tt, ff;
    if (fi < 2)       { src = W1;  ncols = 32; tt = fi;            ff = 0; }
    else if (fi < 8)  { src = W2;  ncols = 96; tt = fi - 2;        ff = 0; }
    else if (fi < 26) { src = WA;  ncols = 96; tt = (fi - 8) / 3;  ff = (fi - 8) % 3; }
    else if (fi < 44) { src = WL;  ncols = 96; tt = (fi - 26) / 3; ff = (fi - 26) % 3; }
    else              { src = WL2; ncols = 96; tt = (fi - 44) / 3; ff = (fi - 44) % 3; }
    int k = ff * 32 + q * 8 + j;
    int n = tt * 16 + ln;
    wB[tid] = f2bf(src[k * ncols + n]);
}

// ---------------------------------------------------------------------------
// Fused edge pipeline: radial MLP -> msg -> {logits, value}, all MFMA.
// 64 edges / block, 256 threads (4 waves); wave w owns m-tile rows w*16..+15.
// ---------------------------------------------------------------------------
__global__ __launch_bounds__(256, 4) void fused_edge_kernel(
    const float* __restrict__ message, const float* __restrict__ ea,
    const float* __restrict__ xs,
    const float* __restrict__ b1, const float* __restrict__ b2,
    const float* __restrict__ wdtp2, const float* __restrict__ adot,
    const short* __restrict__ wB,
    ushort* __restrict__ value, float* __restrict__ logits, int E)
{
    __shared__ __align__(16) short sA[64 * 104];     // msg bf16, padded rows
    __shared__ __align__(16) char  uni[64 * 97 * 4]; // hid bf16 / slrelu fp32 / A2 bf16
    short* sB = (short*)uni;
    float* sS = (float*)uni;
    const short8* wB8 = (const short8*)wB;

    const int t    = threadIdx.x;
    const int lane = t & 63;
    const int w    = t >> 6;
    const int q    = lane >> 4;
    const int ln   = lane & 15;
    const int row0 = blockIdx.x * 64;

    const int mA = w * 16 + ln;      // A-operand local row for this lane
    const int gA = row0 + mA;
    const int mC = w * 16 + q * 4;   // C/D local row base (add reg r)

    // ---- Phase A1: hid = silu(xs @ W1 + b1) -> sB (bf16, stride 104) ----
    short8 af;
    {
        float4 x0 = make_float4(0, 0, 0, 0), x1 = x0;
        if (gA < E) {
            const float4* p = (const float4*)&xs[(size_t)gA * S + q * 8];
            x0 = p[0]; x1 = p[1];
        }
        af[0] = f2bf(x0.x); af[1] = f2bf(x0.y); af[2] = f2bf(x0.z); af[3] = f2bf(x0.w);
        af[4] = f2bf(x1.x); af[5] = f2bf(x1.y); af[6] = f2bf(x1.z); af[7] = f2bf(x1.w);
    }
    {
        f32x4 h0 = {0, 0, 0, 0}, h1 = {0, 0, 0, 0};
        h0 = MFMA(af, wB8[0 * 64 + lane], h0);
        h1 = MFMA(af, wB8[1 * 64 + lane], h1);
#pragma unroll
        for (int r = 0; r < 4; r++) {
            sB[(mC + r) * 104 + ln]      = f2bf(siluf_(h0[r] + b1[ln]));
            sB[(mC + r) * 104 + 16 + ln] = f2bf(siluf_(h1[r] + b1[16 + ln]));
        }
    }
    __syncthreads();

    // ---- Phase A2: weight = hid@W2 + b2; msg = message*ea*weight -> sA ----
    f32x4 acc[6];
    {
        short8 hf = *(const short8*)&sB[mA * 104 + q * 8];
#pragma unroll
        for (int i = 0; i < 6; i++) acc[i] = (f32x4){0, 0, 0, 0};
#pragma unroll
        for (int i = 0; i < 6; i++) acc[i] = MFMA(hf, wB8[(2 + i) * 64 + lane], acc[i]);
    }
    float eaR[4];
#pragma unroll
    for (int r = 0; r < 4; r++) {
        int gm = row0 + mC + r;
        eaR[r] = (gm < E) ? ea[gm] : 0.0f;
    }
#pragma unroll
    for (int i = 0; i < 6; i++) {
        int n = i * 16 + ln;
#pragma unroll
        for (int r = 0; r < 4; r++) {
            int gm = row0 + mC + r;
            float mv = (gm < E) ? message[(size_t)gm * D + n] : 0.0f;
            sA[(mC + r) * 104 + n] = f2bf(mv * eaR[r] * (acc[i][r] + b2[n]));
        }
    }
    __syncthreads();

    // ---- msg A-frags (reused in phases B and C1) ----
    short8 mf0 = *(const short8*)&sA[mA * 104 + 0  + q * 8];
    short8 mf1 = *(const short8*)&sA[mA * 104 + 32 + q * 8];
    short8 mf2 = *(const short8*)&sA[mA * 104 + 64 + q * 8];

    // ---- Phase B: P1 = msg @ W_alpha; slrelu -> sS; logits ----
#pragma unroll
    for (int i = 0; i < 6; i++) acc[i] = (f32x4){0, 0, 0, 0};
#pragma unroll
    for (int i = 0; i < 6; i++) {
        acc[i] = MFMA(mf0, wB8[(8 + i * 3 + 0) * 64 + lane], acc[i]);
        acc[i] = MFMA(mf1, wB8[(8 + i * 3 + 1) * 64 + lane], acc[i]);
        acc[i] = MFMA(mf2, wB8[(8 + i * 3 + 2) * 64 + lane], acc[i]);
    }
#pragma unroll
    for (int i = 0; i < 6; i++) {
        int n = i * 16 + ln;
#pragma unroll
        for (int r = 0; r < 4; r++)
            sS[(mC + r) * 97 + n] = slrelu_(acc[i][r]);
    }
    __syncthreads();
    {
        int e = t & 63;
        int gm = row0 + e;
#pragma unroll
        for (int hh = 0; hh < 2; hh++) {
            int h = (t >> 6) * 2 + hh;
            float lg = 0.0f;
#pragma unroll
            for (int k = 0; k < KH; k++)
                lg += sS[e * 97 + h * KH + k] * adot[h * KH + k];
            if (gm < E) logits[(size_t)gm * H + h] = lg;
        }
    }
    __syncthreads();

    // ---- Phase C1: A2 = silu(msg@W_lin)*ea*wdtp2 -> sB (bf16) ----
#pragma unroll
    for (int i = 0; i < 6; i++) acc[i] = (f32x4){0, 0, 0, 0};
#pragma unroll
    for (int i = 0; i < 6; i++) {
        acc[i] = MFMA(mf0, wB8[(26 + i * 3 + 0) * 64 + lane], acc[i]);
        acc[i] = MFMA(mf1, wB8[(26 + i * 3 + 1) * 64 + lane], acc[i]);
        acc[i] = MFMA(mf2, wB8[(26 + i * 3 + 2) * 64 + lane], acc[i]);
    }
#pragma unroll
    for (int i = 0; i < 6; i++) {
        int n = i * 16 + ln;
#pragma unroll
        for (int r = 0; r < 4; r++)
            sB[(mC + r) * 104 + n] = f2bf(siluf_(acc[i][r]) * eaR[r] * wdtp2[n]);
    }
    __syncthreads();

    // ---- Phase C2: value = A2 @ W_lin2 -> global (bf16) ----
    {
        short8 vf0 = *(const short8*)&sB[mA * 104 + 0  + q * 8];
        short8 vf1 = *(const short8*)&sB[mA * 104 + 32 + q * 8];
        short8 vf2 = *(const short8*)&sB[mA * 104 + 64 + q * 8];
#pragma unroll
        for (int i = 0; i < 6; i++) acc[i] = (f32x4){0, 0, 0, 0};
#pragma unroll
        for (int i = 0; i < 6; i++) {
            acc[i] = MFMA(vf0, wB8[(44 + i * 3 + 0) * 64 + lane], acc[i]);
            acc[i] = MFMA(vf1, wB8[(44 + i * 3 + 1) * 64 + lane], acc[i]);
            acc[i] = MFMA(vf2, wB8[(44 + i * 3 + 2) * 64 + lane], acc[i]);
        }
#pragma unroll
        for (int i = 0; i < 6; i++) {
            int n = i * 16 + ln;
#pragma unroll
            for (int r = 0; r < 4; r++) {
                int gm = row0 + mC + r;
                if (gm < E) value[(size_t)gm * D + n] = (ushort)f2bf(acc[i][r]);
            }
        }
    }
}

// ---------------------------------------------------------------------------
// Segment log-sum-exp over sorted edge_dst. One thread per (node, head).
// ---------------------------------------------------------------------------
__global__ __launch_bounds__(256) void logz_kernel(
    const float* __restrict__ logits, const int* __restrict__ dst,
    float* __restrict__ logZ, int E, int N)
{
    int tid = blockIdx.x * 256 + threadIdx.x;
    if (tid >= N * H) return;
    int n = tid / H, h = tid % H;
    int lo = 0, hi = E;
    while (lo < hi) {
        int mid = (lo + hi) >> 1;
        if (dst[mid] < n) lo = mid + 1; else hi = mid;
    }
    float m = -INFINITY;
    int e = lo;
    while (e < E && dst[e] == n) { m = fmaxf(m, logits[(size_t)e * H + h]); e++; }
    float z = 0.0f;
    for (int e2 = lo; e2 < e; e2++) z += __expf(logits[(size_t)e2 * H + h] - m);
    logZ[tid] = m + __logf(z);
}

// ---------------------------------------------------------------------------
// Weighted segment-sum: attn[n,d] = sum_e value_bf16[e,d] * alpha[e,h(d)].
// ---------------------------------------------------------------------------
__global__ __launch_bounds__(256) void aggregate_kernel(
    const ushort* __restrict__ value, const float* __restrict__ logits,
    const float* __restrict__ logZ, const int* __restrict__ dst,
    float* __restrict__ attn, int E, int N)
{
    int tid = blockIdx.x * 256 + threadIdx.x;
    if (tid >= N * D) return;
    int n = tid / D, d = tid % D;
    int h = d / KH;
    int lo = 0, hi = E;
    while (lo < hi) {
        int mid = (lo + hi) >> 1;
        if (dst[mid] < n) lo = mid + 1; else hi = mid;
    }
    float lz = logZ[n * H + h];
    float acc = 0.0f;
    for (int e = lo; e < E && dst[e] == n; e++) {
        float a = __expf(logits[(size_t)e * H + h] - lz);
        acc += bf2f(value[(size_t)e * D + d]) * a;
    }
    attn[tid] = acc;
}

// ---------------------------------------------------------------------------
// Final [N,96] @ [96,96] fp32 GEMM (small: N=50k -> ~40us).
// ---------------------------------------------------------------------------
__global__ __launch_bounds__(192) void gemm96_out_kernel(
    const float* __restrict__ src, const float* __restrict__ W,
    float* __restrict__ dst, int rows)
{
    __shared__ float sW[D * D];
    __shared__ float tile[64 * (D + 1)];

    const int t = threadIdx.x;
    const int row0 = blockIdx.x * 64;

    for (int i = t; i < D * D; i += 192) sW[i] = W[i];
    for (int i = t; i < 64 * D; i += 192) {
        int e = i / D, d = i % D;
        int r = row0 + e;
        tile[e * (D + 1) + d] = (r < rows) ? src[(size_t)r * D + d] : 0.0f;
    }
    __syncthreads();

    const int e0 = (t & 15) * 4;
    const int d0 = (t >> 4) * 8;

    float acc[4][8];
#pragma unroll
    for (int a = 0; a < 4; a++)
#pragma unroll
        for (int j = 0; j < 8; j++) acc[a][j] = 0.0f;

    for (int kk = 0; kk < D; kk++) {
        float4 w0 = *(const float4*)&sW[kk * D + d0];
        float4 w1 = *(const float4*)&sW[kk * D + d0 + 4];
#pragma unroll
        for (int a = 0; a < 4; a++) {
            float m = tile[(e0 + a) * (D + 1) + kk];
            acc[a][0] += m * w0.x; acc[a][1] += m * w0.y;
            acc[a][2] += m * w0.z; acc[a][3] += m * w0.w;
            acc[a][4] += m * w1.x; acc[a][5] += m * w1.y;
            acc[a][6] += m * w1.z; acc[a][7] += m * w1.w;
        }
    }
#pragma unroll
    for (int a = 0; a < 4; a++) {
        int r = row0 + e0 + a;
        if (r >= rows) continue;
        *(float4*)&dst[(size_t)r * D + d0]     = make_float4(acc[a][0], acc[a][1], acc[a][2], acc[a][3]);
        *(float4*)&dst[(size_t)r * D + d0 + 4] = make_float4(acc[a][4], acc[a][5], acc[a][6], acc[a][7]);
    }
}

// ---------------------------------------------------------------------------
extern "C" void kernel_launch(void* const* d_in, const int* in_sizes, int n_in,
                              void* d_out, int out_size, void* d_ws, size_t ws_size,
                              hipStream_t stream)
{
    const float* message      = (const float*)d_in[0];
    const float* edge_attr    = (const float*)d_in[1];
    const float* edge_scalars = (const float*)d_in[2];
    const float* W_rad1       = (const float*)d_in[3];
    const float* b_rad1       = (const float*)d_in[4];
    const float* W_rad2       = (const float*)d_in[5];
    const float* b_rad2       = (const float*)d_in[6];
    const float* W_alpha      = (const float*)d_in[7];
    const float* W_lin        = (const float*)d_in[8];
    const float* w_dtp2       = (const float*)d_in[9];
    const float* W_lin2       = (const float*)d_in[10];
    const float* alpha_dot    = (const float*)d_in[11];
    const float* W_proj       = (const float*)d_in[12];
    const int*   edge_dst     = (const int*)d_in[13];
    float* out = (float*)d_out;

    const int E = in_sizes[0] / D;
    const int N = out_size / D;

    char* ws = (char*)d_ws;
    ushort* value  = (ushort*)ws;                               // E*96 bf16
    float*  logits = (float*)(ws + (size_t)E * D * 2);          // E*8  f32
    float*  logZ   = (float*)((char*)logits + (size_t)E * H * 4); // N*8
    float*  attn   = (float*)((char*)logZ + (size_t)N * H * 4);   // N*96
    short*  wBuf   = (short*)((char*)attn + (size_t)N * D * 4);   // 62*512 bf16

    pack_weights_kernel<<<(62 * 512 + 255) / 256, 256, 0, stream>>>(
        W_rad1, W_rad2, W_alpha, W_lin, W_lin2, wBuf);
    fused_edge_kernel<<<(E + 63) / 64, 256, 0, stream>>>(
        message, edge_attr, edge_scalars, b_rad1, b_rad2, w_dtp2, alpha_dot,
        wBuf, value, logits, E);
    logz_kernel<<<(N * H + 255) / 256, 256, 0, stream>>>(logits, edge_dst, logZ, E, N);
    aggregate_kernel<<<(N * D + 255) / 256, 256, 0, stream>>>(value, logits, logZ,
                                                              edge_dst, attn, E, N);
    gemm96_out_kernel<<<(N + 63) / 64, 192, 0, stream>>>(attn, W_proj, out, N);
}

// Round 3
// 876.135 us; speedup vs baseline: 3.3682x; 1.1844x over previous
//
#include <hip/hip_runtime.h>
#include <hip/hip_bf16.h>
#include <math.h>

#define D 96
#define H 8
#define KH 12
#define S 32

typedef __attribute__((ext_vector_type(8))) short short8;
typedef __attribute__((ext_vector_type(4))) float f32x4;

#define MFMA(a, b, c) __builtin_amdgcn_mfma_f32_16x16x32_bf16(a, b, c, 0, 0, 0)

__device__ __forceinline__ float sigmoidf_(float x) { return 1.0f / (1.0f + __expf(-x)); }
__device__ __forceinline__ float siluf_(float x) { return x * sigmoidf_(x); }
__device__ __forceinline__ float slrelu_(float x) {
    float s = sigmoidf_(x);
    return 0.6f * x + 0.4f * x * (2.0f * s - 1.0f);
}
__device__ __forceinline__ short f2bf(float f) {
    unsigned int u = __float_as_uint(f);
    u += 0x7fffu + ((u >> 16) & 1u);
    return (short)(u >> 16);
}
__device__ __forceinline__ float bf2f(ushort u) {
    return __uint_as_float(((unsigned int)u) << 16);
}

// ---------------------------------------------------------------------------
// Pack weights into MFMA B-fragment-ready bf16 layout (see R2 notes).
// Lane l of frag holds B[k = f*32 + (l>>4)*8 + j][n = t*16 + (l&15)], j=0..7.
// ---------------------------------------------------------------------------
__global__ void pack_weights_kernel(
    const float* __restrict__ W1, const float* __restrict__ W2,
    const float* __restrict__ WA, const float* __restrict__ WL,
    const float* __restrict__ WL2, short* __restrict__ wB)
{
    int tid = blockIdx.x * 256 + threadIdx.x;
    if (tid >= 62 * 512) return;
    int j    = tid & 7;
    int lane = (tid >> 3) & 63;
    int fi   = tid >> 9;
    int q = lane >> 4, ln = lane & 15;
    const float* src; int ncols, tt, ff;
    if (fi < 2)       { src = W1;  ncols = 32; tt = fi;            ff = 0; }
    else if (fi < 8)  { src = W2;  ncols = 96; tt = fi - 2;        ff = 0; }
    else if (fi < 26) { src = WA;  ncols = 96; tt = (fi - 8) / 3;  ff = (fi - 8) % 3; }
    else if (fi < 44) { src = WL;  ncols = 96; tt = (fi - 26) / 3; ff = (fi - 26) % 3; }
    else              { src = WL2; ncols = 96; tt = (fi - 44) / 3; ff = (fi - 44) % 3; }
    int k = ff * 32 + q * 8 + j;
    int n = tt * 16 + ln;
    wB[tid] = f2bf(src[k * ncols + n]);
}

// ---------------------------------------------------------------------------
// row_ptr[n] = first edge with dst >= n (edge_dst is sorted). rp has N+1 ents.
// ---------------------------------------------------------------------------
__global__ __launch_bounds__(256) void rowptr_kernel(
    const int* __restrict__ dst, int* __restrict__ rp, int E, int N)
{
    int e = blockIdx.x * 256 + threadIdx.x;
    if (e >= E) return;
    int cur  = dst[e];
    int prev = (e == 0) ? -1 : dst[e - 1];
    for (int n = prev + 1; n <= cur; n++) rp[n] = e;
    if (e == E - 1)
        for (int n = cur + 1; n <= N; n++) rp[n] = E;
}

// ---------------------------------------------------------------------------
// Fused edge pipeline: radial MLP -> msg -> {logits, value}, all MFMA.
// 64 edges/block, 4 waves; wave w owns rows w*16..w*16+15 of every LDS view.
// Single 24.8KB union buffer; all LDS use is intra-wave-slab except the
// slrelu->logits reduction, so only 3 barriers are needed (see analysis).
// ---------------------------------------------------------------------------
__global__ __launch_bounds__(256, 6) void fused_edge_kernel(
    const float* __restrict__ message, const float* __restrict__ ea,
    const float* __restrict__ xs,
    const float* __restrict__ b1, const float* __restrict__ b2,
    const float* __restrict__ wdtp2, const float* __restrict__ adot,
    const short* __restrict__ wB,
    ushort* __restrict__ value, float* __restrict__ logits, int E)
{
    __shared__ __align__(16) char uni[64 * 97 * 4];   // 24832 B union buffer
    short* sB = (short*)uni;   // bf16 views, row stride 104 shorts (208 B)
    float* sS = (float*)uni;   // fp32 slrelu view, row stride 97 (388 B)
    const short8* wB8 = (const short8*)wB;

    const int t    = threadIdx.x;
    const int lane = t & 63;
    const int w    = t >> 6;
    const int q    = lane >> 4;
    const int ln   = lane & 15;
    const int row0 = blockIdx.x * 64;

    const int mA = w * 16 + ln;      // A-operand local row for this lane
    const int gA = row0 + mA;
    const int mC = w * 16 + q * 4;   // C/D local row base (add reg r)

    // ---- Phase A1: hid = silu(xs @ W1 + b1) -> sB bf16 (own slab) ----
    short8 af;
    {
        float4 x0 = make_float4(0, 0, 0, 0), x1 = x0;
        if (gA < E) {
            const float4* p = (const float4*)&xs[(size_t)gA * S + q * 8];
            x0 = p[0]; x1 = p[1];
        }
        af[0] = f2bf(x0.x); af[1] = f2bf(x0.y); af[2] = f2bf(x0.z); af[3] = f2bf(x0.w);
        af[4] = f2bf(x1.x); af[5] = f2bf(x1.y); af[6] = f2bf(x1.z); af[7] = f2bf(x1.w);
    }
    {
        f32x4 h0 = {0, 0, 0, 0}, h1 = {0, 0, 0, 0};
        h0 = MFMA(af, wB8[0 * 64 + lane], h0);
        h1 = MFMA(af, wB8[1 * 64 + lane], h1);
#pragma unroll
        for (int r = 0; r < 4; r++) {
            sB[(mC + r) * 104 + ln]      = f2bf(siluf_(h0[r] + b1[ln]));
            sB[(mC + r) * 104 + 16 + ln] = f2bf(siluf_(h1[r] + b1[16 + ln]));
        }
    }
    // no barrier: hid write/read confined to own wave slab, DS in-order

    // ---- Phase A2: weight = hid@W2 + b2; msg = message*ea*weight -> sB ----
    f32x4 acc[6];
    {
        short8 hf = *(const short8*)&sB[mA * 104 + q * 8];
#pragma unroll
        for (int i = 0; i < 6; i++) acc[i] = (f32x4){0, 0, 0, 0};
#pragma unroll
        for (int i = 0; i < 6; i++) acc[i] = MFMA(hf, wB8[(2 + i) * 64 + lane], acc[i]);
    }
    float eaR[4];
#pragma unroll
    for (int r = 0; r < 4; r++) {
        int gm = row0 + mC + r;
        eaR[r] = (gm < E) ? ea[gm] : 0.0f;
    }
#pragma unroll
    for (int i = 0; i < 6; i++) {
        int n = i * 16 + ln;
#pragma unroll
        for (int r = 0; r < 4; r++) {
            int gm = row0 + mC + r;
            float mv = (gm < E) ? message[(size_t)gm * D + n] : 0.0f;
            sB[(mC + r) * 104 + n] = f2bf(mv * eaR[r] * (acc[i][r] + b2[n]));
        }
    }
    // no barrier: msg write/read confined to own wave slab

    // ---- msg A-frags (reused in phases B and C1) ----
    short8 mf0 = *(const short8*)&sB[mA * 104 + 0  + q * 8];
    short8 mf1 = *(const short8*)&sB[mA * 104 + 32 + q * 8];
    short8 mf2 = *(const short8*)&sB[mA * 104 + 64 + q * 8];
    __syncthreads();   // (1) protect msg slabs from cross-wave slrelu writes

    // ---- Phase B: P1 = msg @ W_alpha; slrelu -> sS; logits ----
#pragma unroll
    for (int i = 0; i < 6; i++) acc[i] = (f32x4){0, 0, 0, 0};
#pragma unroll
    for (int i = 0; i < 6; i++) {
        acc[i] = MFMA(mf0, wB8[(8 + i * 3 + 0) * 64 + lane], acc[i]);
        acc[i] = MFMA(mf1, wB8[(8 + i * 3 + 1) * 64 + lane], acc[i]);
        acc[i] = MFMA(mf2, wB8[(8 + i * 3 + 2) * 64 + lane], acc[i]);
    }
#pragma unroll
    for (int i = 0; i < 6; i++) {
        int n = i * 16 + ln;
#pragma unroll
        for (int r = 0; r < 4; r++)
            sS[(mC + r) * 97 + n] = slrelu_(acc[i][r]);
    }
    __syncthreads();   // (2) slrelu visible to all waves
    {
        int e = t & 63;
        int gm = row0 + e;
#pragma unroll
        for (int hh = 0; hh < 2; hh++) {
            int h = (t >> 6) * 2 + hh;
            float lg = 0.0f;
#pragma unroll
            for (int k = 0; k < KH; k++)
                lg += sS[e * 97 + h * KH + k] * adot[h * KH + k];
            if (gm < E) logits[(size_t)gm * H + h] = lg;
        }
    }
    __syncthreads();   // (3) reduce reads done before C1 overwrites buffer

    // ---- Phase C1: A2 = silu(msg@W_lin)*ea*wdtp2 -> sB (own slab) ----
#pragma unroll
    for (int i = 0; i < 6; i++) acc[i] = (f32x4){0, 0, 0, 0};
#pragma unroll
    for (int i = 0; i < 6; i++) {
        acc[i] = MFMA(mf0, wB8[(26 + i * 3 + 0) * 64 + lane], acc[i]);
        acc[i] = MFMA(mf1, wB8[(26 + i * 3 + 1) * 64 + lane], acc[i]);
        acc[i] = MFMA(mf2, wB8[(26 + i * 3 + 2) * 64 + lane], acc[i]);
    }
#pragma unroll
    for (int i = 0; i < 6; i++) {
        int n = i * 16 + ln;
#pragma unroll
        for (int r = 0; r < 4; r++)
            sB[(mC + r) * 104 + n] = f2bf(siluf_(acc[i][r]) * eaR[r] * wdtp2[n]);
    }
    // no barrier: A2 write + C2 frag read confined to own wave slab

    // ---- Phase C2: value = A2 @ W_lin2 -> global (bf16) ----
    {
        short8 vf0 = *(const short8*)&sB[mA * 104 + 0  + q * 8];
        short8 vf1 = *(const short8*)&sB[mA * 104 + 32 + q * 8];
        short8 vf2 = *(const short8*)&sB[mA * 104 + 64 + q * 8];
#pragma unroll
        for (int i = 0; i < 6; i++) acc[i] = (f32x4){0, 0, 0, 0};
#pragma unroll
        for (int i = 0; i < 6; i++) {
            acc[i] = MFMA(vf0, wB8[(44 + i * 3 + 0) * 64 + lane], acc[i]);
            acc[i] = MFMA(vf1, wB8[(44 + i * 3 + 1) * 64 + lane], acc[i]);
            acc[i] = MFMA(vf2, wB8[(44 + i * 3 + 2) * 64 + lane], acc[i]);
        }
#pragma unroll
        for (int i = 0; i < 6; i++) {
            int n = i * 16 + ln;
#pragma unroll
            for (int r = 0; r < 4; r++) {
                int gm = row0 + mC + r;
                if (gm < E) value[(size_t)gm * D + n] = (ushort)f2bf(acc[i][r]);
            }
        }
    }
}

// ---------------------------------------------------------------------------
// Segment softmax: per (node, head), counted loop via row_ptr.
// Writes normalized alpha[e,h] = exp(l - m) / z.
// ---------------------------------------------------------------------------
__global__ __launch_bounds__(256) void logz_alpha_kernel(
    const float* __restrict__ logits, const int* __restrict__ rp,
    float* __restrict__ alpha, int N)
{
    int tid = blockIdx.x * 256 + threadIdx.x;
    if (tid >= N * H) return;
    int n = tid >> 3, h = tid & 7;
    int s = rp[n], e1 = rp[n + 1];
    if (s >= e1) return;
    float m = -INFINITY;
    for (int e = s; e < e1; e++) m = fmaxf(m, logits[(size_t)e * H + h]);
    float z = 0.0f;
    for (int e = s; e < e1; e++) {
        float a = __expf(logits[(size_t)e * H + h] - m);
        z += a;
        alpha[(size_t)e * H + h] = a;
    }
    float inv = 1.0f / z;
    for (int e = s; e < e1; e++) alpha[(size_t)e * H + h] *= inv;
}

// ---------------------------------------------------------------------------
// Weighted segment-sum: attn[n,d] = sum_seg value[e,d] * alpha[e,h(d)].
// Counted loop, no exp, no dst loads.
// ---------------------------------------------------------------------------
__global__ __launch_bounds__(256) void aggregate_kernel(
    const ushort* __restrict__ value, const float* __restrict__ alpha,
    const int* __restrict__ rp, float* __restrict__ attn, int N)
{
    int tid = blockIdx.x * 256 + threadIdx.x;
    if (tid >= N * D) return;
    int n = tid / D, d = tid % D;
    int h = d / KH;
    int s = rp[n], e1 = rp[n + 1];
    float acc = 0.0f;
    for (int e = s; e < e1; e++)
        acc += bf2f(value[(size_t)e * D + d]) * alpha[(size_t)e * H + h];
    attn[tid] = acc;
}

// ---------------------------------------------------------------------------
// Final [N,96] @ [96,96] fp32 GEMM.
// ---------------------------------------------------------------------------
__global__ __launch_bounds__(192) void gemm96_out_kernel(
    const float* __restrict__ src, const float* __restrict__ W,
    float* __restrict__ dst, int rows)
{
    __shared__ float sW[D * D];
    __shared__ float tile[64 * (D + 1)];

    const int t = threadIdx.x;
    const int row0 = blockIdx.x * 64;

    for (int i = t; i < D * D; i += 192) sW[i] = W[i];
    for (int i = t; i < 64 * D; i += 192) {
        int e = i / D, d = i % D;
        int r = row0 + e;
        tile[e * (D + 1) + d] = (r < rows) ? src[(size_t)r * D + d] : 0.0f;
    }
    __syncthreads();

    const int e0 = (t & 15) * 4;
    const int d0 = (t >> 4) * 8;

    float acc[4][8];
#pragma unroll
    for (int a = 0; a < 4; a++)
#pragma unroll
        for (int j = 0; j < 8; j++) acc[a][j] = 0.0f;

    for (int kk = 0; kk < D; kk++) {
        float4 w0 = *(const float4*)&sW[kk * D + d0];
        float4 w1 = *(const float4*)&sW[kk * D + d0 + 4];
#pragma unroll
        for (int a = 0; a < 4; a++) {
            float m = tile[(e0 + a) * (D + 1) + kk];
            acc[a][0] += m * w0.x; acc[a][1] += m * w0.y;
            acc[a][2] += m * w0.z; acc[a][3] += m * w0.w;
            acc[a][4] += m * w1.x; acc[a][5] += m * w1.y;
            acc[a][6] += m * w1.z; acc[a][7] += m * w1.w;
        }
    }
#pragma unroll
    for (int a = 0; a < 4; a++) {
        int r = row0 + e0 + a;
        if (r >= rows) continue;
        *(float4*)&dst[(size_t)r * D + d0]     = make_float4(acc[a][0], acc[a][1], acc[a][2], acc[a][3]);
        *(float4*)&dst[(size_t)r * D + d0 + 4] = make_float4(acc[a][4], acc[a][5], acc[a][6], acc[a][7]);
    }
}

// ---------------------------------------------------------------------------
extern "C" void kernel_launch(void* const* d_in, const int* in_sizes, int n_in,
                              void* d_out, int out_size, void* d_ws, size_t ws_size,
                              hipStream_t stream)
{
    const float* message      = (const float*)d_in[0];
    const float* edge_attr    = (const float*)d_in[1];
    const float* edge_scalars = (const float*)d_in[2];
    const float* W_rad1       = (const float*)d_in[3];
    const float* b_rad1       = (const float*)d_in[4];
    const float* W_rad2       = (const float*)d_in[5];
    const float* b_rad2       = (const float*)d_in[6];
    const float* W_alpha      = (const float*)d_in[7];
    const float* W_lin        = (const float*)d_in[8];
    const float* w_dtp2       = (const float*)d_in[9];
    const float* W_lin2       = (const float*)d_in[10];
    const float* alpha_dot    = (const float*)d_in[11];
    const float* W_proj       = (const float*)d_in[12];
    const int*   edge_dst     = (const int*)d_in[13];
    float* out = (float*)d_out;

    const int E = in_sizes[0] / D;
    const int N = out_size / D;

    char* ws = (char*)d_ws;
    ushort* value  = (ushort*)ws;                                   // E*96 bf16
    float*  logits = (float*)(ws + (size_t)E * D * 2);              // E*8  f32
    float*  alphaB = (float*)((char*)logits + (size_t)E * H * 4);   // E*8  f32
    float*  attn   = (float*)((char*)alphaB + (size_t)E * H * 4);   // N*96 f32
    int*    rp     = (int*)((char*)attn + (size_t)N * D * 4);       // N+1
    short*  wBuf   = (short*)((char*)rp + (size_t)(N + 1) * 4);     // 62*512 bf16

    pack_weights_kernel<<<(62 * 512 + 255) / 256, 256, 0, stream>>>(
        W_rad1, W_rad2, W_alpha, W_lin, W_lin2, wBuf);
    rowptr_kernel<<<(E + 255) / 256, 256, 0, stream>>>(edge_dst, rp, E, N);
    fused_edge_kernel<<<(E + 63) / 64, 256, 0, stream>>>(
        message, edge_attr, edge_scalars, b_rad1, b_rad2, w_dtp2, alpha_dot,
        wBuf, value, logits, E);
    logz_alpha_kernel<<<(N * H + 255) / 256, 256, 0, stream>>>(logits, rp, alphaB, N);
    aggregate_kernel<<<(N * D + 255) / 256, 256, 0, stream>>>(value, alphaB, rp, attn, N);
    gemm96_out_kernel<<<(N + 63) / 64, 192, 0, stream>>>(attn, W_proj, out, N);
}

// Round 4
// 783.986 us; speedup vs baseline: 3.7641x; 1.1175x over previous
//
#include <hip/hip_runtime.h>
#include <hip/hip_bf16.h>
#include <math.h>

#define D 96
#define H 8
#define KH 12
#define S 32

typedef __attribute__((ext_vector_type(8))) short short8;
typedef __attribute__((ext_vector_type(4))) float f32x4;

#define MFMA(a, b, c) __builtin_amdgcn_mfma_f32_16x16x32_bf16(a, b, c, 0, 0, 0)

__device__ __forceinline__ float sigmoidf_(float x) { return 1.0f / (1.0f + __expf(-x)); }
__device__ __forceinline__ float siluf_(float x) { return x * sigmoidf_(x); }
__device__ __forceinline__ float slrelu_(float x) {
    float s = sigmoidf_(x);
    return 0.6f * x + 0.4f * x * (2.0f * s - 1.0f);
}
__device__ __forceinline__ short f2bf(float f) {
    unsigned int u = __float_as_uint(f);
    u += 0x7fffu + ((u >> 16) & 1u);
    return (short)(u >> 16);
}
__device__ __forceinline__ float bf2f(ushort u) {
    return __uint_as_float(((unsigned int)u) << 16);
}

// ---------------------------------------------------------------------------
// Pack weights into MFMA B-fragment-ready bf16 layout. 80 frags total:
//   0..1  W1(32x32)  2..7  W2(32x96)  8..25 Walpha  26..43 Wlin
//   44..61 Wlin2     62..79 Wproj     (all 96x96 use t=/3, f=%3)
// Lane l of frag holds B[k = f*32 + (l>>4)*8 + j][n = t*16 + (l&15)], j=0..7.
// ---------------------------------------------------------------------------
__global__ void pack_weights_kernel(
    const float* __restrict__ W1, const float* __restrict__ W2,
    const float* __restrict__ WA, const float* __restrict__ WL,
    const float* __restrict__ WL2, const float* __restrict__ WP,
    short* __restrict__ wB)
{
    int tid = blockIdx.x * 256 + threadIdx.x;
    if (tid >= 80 * 512) return;
    int j    = tid & 7;
    int lane = (tid >> 3) & 63;
    int fi   = tid >> 9;
    int q = lane >> 4, ln = lane & 15;
    const float* src; int ncols, tt, ff;
    if (fi < 2)       { src = W1;  ncols = 32; tt = fi;            ff = 0; }
    else if (fi < 8)  { src = W2;  ncols = 96; tt = fi - 2;        ff = 0; }
    else if (fi < 26) { src = WA;  ncols = 96; tt = (fi - 8) / 3;  ff = (fi - 8) % 3; }
    else if (fi < 44) { src = WL;  ncols = 96; tt = (fi - 26) / 3; ff = (fi - 26) % 3; }
    else if (fi < 62) { src = WL2; ncols = 96; tt = (fi - 44) / 3; ff = (fi - 44) % 3; }
    else              { src = WP;  ncols = 96; tt = (fi - 62) / 3; ff = (fi - 62) % 3; }
    int k = ff * 32 + q * 8 + j;
    int n = tt * 16 + ln;
    wB[tid] = f2bf(src[k * ncols + n]);
}

// ---------------------------------------------------------------------------
// row_ptr[n] = first edge with dst >= n (edge_dst sorted). rp has N+1 entries.
// ---------------------------------------------------------------------------
__global__ __launch_bounds__(256) void rowptr_kernel(
    const int* __restrict__ dst, int* __restrict__ rp, int E, int N)
{
    int e = blockIdx.x * 256 + threadIdx.x;
    if (e >= E) return;
    int cur  = dst[e];
    int prev = (e == 0) ? -1 : dst[e - 1];
    for (int n = prev + 1; n <= cur; n++) rp[n] = e;
    if (e == E - 1)
        for (int n = cur + 1; n <= N; n++) rp[n] = E;
}

// ---------------------------------------------------------------------------
// Fused edge pipeline: radial MLP -> msg -> {logits, value}, all MFMA.
// 64 edges/block, 4 waves; wave w owns rows w*16..w*16+15 of every LDS view.
// ---------------------------------------------------------------------------
__global__ __launch_bounds__(256, 6) void fused_edge_kernel(
    const float* __restrict__ message, const float* __restrict__ ea,
    const float* __restrict__ xs,
    const float* __restrict__ b1, const float* __restrict__ b2,
    const float* __restrict__ wdtp2, const float* __restrict__ adot,
    const short* __restrict__ wB,
    ushort* __restrict__ value, float* __restrict__ logits, int E)
{
    __shared__ __align__(16) char uni[64 * 97 * 4];   // 24832 B union buffer
    short* sB = (short*)uni;   // bf16 views, row stride 104 shorts
    float* sS = (float*)uni;   // fp32 slrelu view, row stride 97
    const short8* wB8 = (const short8*)wB;

    const int t    = threadIdx.x;
    const int lane = t & 63;
    const int w    = t >> 6;
    const int q    = lane >> 4;
    const int ln   = lane & 15;
    const int row0 = blockIdx.x * 64;

    const int mA = w * 16 + ln;
    const int gA = row0 + mA;
    const int mC = w * 16 + q * 4;

    // ---- Phase A1: hid = silu(xs @ W1 + b1) -> sB bf16 (own slab) ----
    short8 af;
    {
        float4 x0 = make_float4(0, 0, 0, 0), x1 = x0;
        if (gA < E) {
            const float4* p = (const float4*)&xs[(size_t)gA * S + q * 8];
            x0 = p[0]; x1 = p[1];
        }
        af[0] = f2bf(x0.x); af[1] = f2bf(x0.y); af[2] = f2bf(x0.z); af[3] = f2bf(x0.w);
        af[4] = f2bf(x1.x); af[5] = f2bf(x1.y); af[6] = f2bf(x1.z); af[7] = f2bf(x1.w);
    }
    {
        f32x4 h0 = {0, 0, 0, 0}, h1 = {0, 0, 0, 0};
        h0 = MFMA(af, wB8[0 * 64 + lane], h0);
        h1 = MFMA(af, wB8[1 * 64 + lane], h1);
#pragma unroll
        for (int r = 0; r < 4; r++) {
            sB[(mC + r) * 104 + ln]      = f2bf(siluf_(h0[r] + b1[ln]));
            sB[(mC + r) * 104 + 16 + ln] = f2bf(siluf_(h1[r] + b1[16 + ln]));
        }
    }
    // no barrier: own wave slab only

    // ---- Phase A2: weight = hid@W2 + b2; msg = message*ea*weight -> sB ----
    f32x4 acc[6];
    {
        short8 hf = *(const short8*)&sB[mA * 104 + q * 8];
#pragma unroll
        for (int i = 0; i < 6; i++) acc[i] = (f32x4){0, 0, 0, 0};
#pragma unroll
        for (int i = 0; i < 6; i++) acc[i] = MFMA(hf, wB8[(2 + i) * 64 + lane], acc[i]);
    }
    float eaR[4];
#pragma unroll
    for (int r = 0; r < 4; r++) {
        int gm = row0 + mC + r;
        eaR[r] = (gm < E) ? ea[gm] : 0.0f;
    }
#pragma unroll
    for (int i = 0; i < 6; i++) {
        int n = i * 16 + ln;
#pragma unroll
        for (int r = 0; r < 4; r++) {
            int gm = row0 + mC + r;
            float mv = (gm < E) ? message[(size_t)gm * D + n] : 0.0f;
            sB[(mC + r) * 104 + n] = f2bf(mv * eaR[r] * (acc[i][r] + b2[n]));
        }
    }
    // no barrier: own wave slab only

    short8 mf0 = *(const short8*)&sB[mA * 104 + 0  + q * 8];
    short8 mf1 = *(const short8*)&sB[mA * 104 + 32 + q * 8];
    short8 mf2 = *(const short8*)&sB[mA * 104 + 64 + q * 8];
    __syncthreads();   // (1) msg frags in regs before slrelu overwrites

    // ---- Phase B: P1 = msg @ W_alpha; slrelu -> sS; logits ----
#pragma unroll
    for (int i = 0; i < 6; i++) acc[i] = (f32x4){0, 0, 0, 0};
#pragma unroll
    for (int i = 0; i < 6; i++) {
        acc[i] = MFMA(mf0, wB8[(8 + i * 3 + 0) * 64 + lane], acc[i]);
        acc[i] = MFMA(mf1, wB8[(8 + i * 3 + 1) * 64 + lane], acc[i]);
        acc[i] = MFMA(mf2, wB8[(8 + i * 3 + 2) * 64 + lane], acc[i]);
    }
#pragma unroll
    for (int i = 0; i < 6; i++) {
        int n = i * 16 + ln;
#pragma unroll
        for (int r = 0; r < 4; r++)
            sS[(mC + r) * 97 + n] = slrelu_(acc[i][r]);
    }
    __syncthreads();   // (2) slrelu visible
    {
        int e = t & 63;
        int gm = row0 + e;
#pragma unroll
        for (int hh = 0; hh < 2; hh++) {
            int h = (t >> 6) * 2 + hh;
            float lg = 0.0f;
#pragma unroll
            for (int k = 0; k < KH; k++)
                lg += sS[e * 97 + h * KH + k] * adot[h * KH + k];
            if (gm < E) logits[(size_t)gm * H + h] = lg;
        }
    }
    __syncthreads();   // (3) reduce done before C1 overwrites

    // ---- Phase C1: A2 = silu(msg@W_lin)*ea*wdtp2 -> sB (own slab) ----
#pragma unroll
    for (int i = 0; i < 6; i++) acc[i] = (f32x4){0, 0, 0, 0};
#pragma unroll
    for (int i = 0; i < 6; i++) {
        acc[i] = MFMA(mf0, wB8[(26 + i * 3 + 0) * 64 + lane], acc[i]);
        acc[i] = MFMA(mf1, wB8[(26 + i * 3 + 1) * 64 + lane], acc[i]);
        acc[i] = MFMA(mf2, wB8[(26 + i * 3 + 2) * 64 + lane], acc[i]);
    }
#pragma unroll
    for (int i = 0; i < 6; i++) {
        int n = i * 16 + ln;
#pragma unroll
        for (int r = 0; r < 4; r++)
            sB[(mC + r) * 104 + n] = f2bf(siluf_(acc[i][r]) * eaR[r] * wdtp2[n]);
    }
    // no barrier: own wave slab only

    // ---- Phase C2: value = A2 @ W_lin2 -> global (bf16) ----
    {
        short8 vf0 = *(const short8*)&sB[mA * 104 + 0  + q * 8];
        short8 vf1 = *(const short8*)&sB[mA * 104 + 32 + q * 8];
        short8 vf2 = *(const short8*)&sB[mA * 104 + 64 + q * 8];
#pragma unroll
        for (int i = 0; i < 6; i++) acc[i] = (f32x4){0, 0, 0, 0};
#pragma unroll
        for (int i = 0; i < 6; i++) {
            acc[i] = MFMA(vf0, wB8[(44 + i * 3 + 0) * 64 + lane], acc[i]);
            acc[i] = MFMA(vf1, wB8[(44 + i * 3 + 1) * 64 + lane], acc[i]);
            acc[i] = MFMA(vf2, wB8[(44 + i * 3 + 2) * 64 + lane], acc[i]);
        }
#pragma unroll
        for (int i = 0; i < 6; i++) {
            int n = i * 16 + ln;
#pragma unroll
            for (int r = 0; r < 4; r++) {
                int gm = row0 + mC + r;
                if (gm < E) value[(size_t)gm * D + n] = (ushort)f2bf(acc[i][r]);
            }
        }
    }
}

// ---------------------------------------------------------------------------
// Segment softmax, 2 passes. Writes UNNORMALIZED alpha and zinv per (n,h).
// ---------------------------------------------------------------------------
__global__ __launch_bounds__(256) void logz_alpha_kernel(
    const float* __restrict__ logits, const int* __restrict__ rp,
    float* __restrict__ alphaU, float* __restrict__ zinv, int N)
{
    int tid = blockIdx.x * 256 + threadIdx.x;
    if (tid >= N * H) return;
    int n = tid >> 3, h = tid & 7;
    int s = rp[n], e1 = rp[n + 1];
    float m = -INFINITY;
    for (int e = s; e < e1; e++) m = fmaxf(m, logits[(size_t)e * H + h]);
    float z = 0.0f;
    for (int e = s; e < e1; e++) {
        float a = __expf(logits[(size_t)e * H + h] - m);
        z += a;
        alphaU[(size_t)e * H + h] = a;
    }
    zinv[tid] = (z > 0.0f) ? (1.0f / z) : 0.0f;
}

// ---------------------------------------------------------------------------
// Vectorized weighted segment-sum. Thread <-> (node, 4-col group g in [0,24)).
// 4 cols always within ONE head (12 = 3*4). Normalization by zinv folded in.
// Output attn as bf16 (feeds MFMA proj).
// ---------------------------------------------------------------------------
__global__ __launch_bounds__(256) void aggregate_kernel(
    const ushort* __restrict__ value, const float* __restrict__ alphaU,
    const float* __restrict__ zinv, const int* __restrict__ rp,
    ushort* __restrict__ attnB, int N)
{
    int tid = blockIdx.x * 256 + threadIdx.x;
    if (tid >= N * 24) return;
    int n = tid / 24, g = tid % 24;
    int d0 = g * 4, h = g / 3;
    int s = rp[n], e1 = rp[n + 1];
    const char* vb = (const char*)value;
    float a0 = 0.0f, a1 = 0.0f, a2 = 0.0f, a3 = 0.0f;
    for (int e = s; e < e1; e++) {
        uint2 v = *(const uint2*)(vb + (size_t)e * 192 + d0 * 2);
        float a = alphaU[(size_t)e * H + h];
        a0 += __uint_as_float(v.x << 16) * a;
        a1 += __uint_as_float(v.x & 0xffff0000u) * a;
        a2 += __uint_as_float(v.y << 16) * a;
        a3 += __uint_as_float(v.y & 0xffff0000u) * a;
    }
    float zi = zinv[n * H + h];
    ushort4 o;
    o.x = (ushort)f2bf(a0 * zi);
    o.y = (ushort)f2bf(a1 * zi);
    o.z = (ushort)f2bf(a2 * zi);
    o.w = (ushort)f2bf(a3 * zi);
    *(ushort4*)&attnB[(size_t)n * D + d0] = o;
}

// ---------------------------------------------------------------------------
// proj: out = attn(bf16) @ W_proj via MFMA. A-frags loaded straight from
// global (16B/lane), W_proj frags 62..79 in wB. 64 rows/block, 4 waves.
// ---------------------------------------------------------------------------
__global__ __launch_bounds__(256) void proj_kernel(
    const ushort* __restrict__ attnB, const short* __restrict__ wB,
    float* __restrict__ out, int rows)
{
    const short8* wB8 = (const short8*)wB;
    const int t    = threadIdx.x;
    const int lane = t & 63;
    const int w    = t >> 6;
    const int q    = lane >> 4;
    const int ln   = lane & 15;
    const int row0 = blockIdx.x * 64;
    const int mA   = w * 16 + ln;
    const int gA   = row0 + mA;
    const int mC   = w * 16 + q * 4;

    short8 mf0 = {0,0,0,0,0,0,0,0}, mf1 = mf0, mf2 = mf0;
    if (gA < rows) {
        mf0 = *(const short8*)&attnB[(size_t)gA * D + 0  + q * 8];
        mf1 = *(const short8*)&attnB[(size_t)gA * D + 32 + q * 8];
        mf2 = *(const short8*)&attnB[(size_t)gA * D + 64 + q * 8];
    }
    f32x4 acc[6];
#pragma unroll
    for (int i = 0; i < 6; i++) acc[i] = (f32x4){0, 0, 0, 0};
#pragma unroll
    for (int i = 0; i < 6; i++) {
        acc[i] = MFMA(mf0, wB8[(62 + i * 3 + 0) * 64 + lane], acc[i]);
        acc[i] = MFMA(mf1, wB8[(62 + i * 3 + 1) * 64 + lane], acc[i]);
        acc[i] = MFMA(mf2, wB8[(62 + i * 3 + 2) * 64 + lane], acc[i]);
    }
#pragma unroll
    for (int i = 0; i < 6; i++) {
        int nn = i * 16 + ln;
#pragma unroll
        for (int r = 0; r < 4; r++) {
            int gm = row0 + mC + r;
            if (gm < rows) out[(size_t)gm * D + nn] = acc[i][r];
        }
    }
}

// ---------------------------------------------------------------------------
extern "C" void kernel_launch(void* const* d_in, const int* in_sizes, int n_in,
                              void* d_out, int out_size, void* d_ws, size_t ws_size,
                              hipStream_t stream)
{
    const float* message      = (const float*)d_in[0];
    const float* edge_attr    = (const float*)d_in[1];
    const float* edge_scalars = (const float*)d_in[2];
    const float* W_rad1       = (const float*)d_in[3];
    const float* b_rad1       = (const float*)d_in[4];
    const float* W_rad2       = (const float*)d_in[5];
    const float* b_rad2       = (const float*)d_in[6];
    const float* W_alpha      = (const float*)d_in[7];
    const float* W_lin        = (const float*)d_in[8];
    const float* w_dtp2       = (const float*)d_in[9];
    const float* W_lin2       = (const float*)d_in[10];
    const float* alpha_dot    = (const float*)d_in[11];
    const float* W_proj       = (const float*)d_in[12];
    const int*   edge_dst     = (const int*)d_in[13];
    float* out = (float*)d_out;

    const int E = in_sizes[0] / D;
    const int N = out_size / D;

    char* p = (char*)d_ws;
    ushort* value  = (ushort*)p;            p += (size_t)E * D * 2;
    float*  logits = (float*)p;             p += (size_t)E * H * 4;
    float*  alphaU = (float*)p;             p += (size_t)E * H * 4;
    float*  zinv   = (float*)p;             p += (size_t)N * H * 4;
    ushort* attnB  = (ushort*)p;            p += (size_t)N * D * 2;
    int*    rp     = (int*)p;               p += ((size_t)(N + 1) * 4 + 15) & ~(size_t)15;
    short*  wBuf   = (short*)p;             // 80*512 bf16

    pack_weights_kernel<<<(80 * 512 + 255) / 256, 256, 0, stream>>>(
        W_rad1, W_rad2, W_alpha, W_lin, W_lin2, W_proj, wBuf);
    rowptr_kernel<<<(E + 255) / 256, 256, 0, stream>>>(edge_dst, rp, E, N);
    fused_edge_kernel<<<(E + 63) / 64, 256, 0, stream>>>(
        message, edge_attr, edge_scalars, b_rad1, b_rad2, w_dtp2, alpha_dot,
        wBuf, value, logits, E);
    logz_alpha_kernel<<<(N * H + 255) / 256, 256, 0, stream>>>(logits, rp, alphaU, zinv, N);
    aggregate_kernel<<<(N * 24 + 255) / 256, 256, 0, stream>>>(value, alphaU, zinv, rp, attnB, N);
    proj_kernel<<<(N + 63) / 64, 256, 0, stream>>>(attnB, wBuf, out, N);
}